// Round 5
// baseline (1675.525 us; speedup 1.0000x reference)
//
#include <hip/hip_runtime.h>
#include <hip/hip_bf16.h>

// AudioLSTM fused persistent kernel, v5.
// B=512, T=1000, IN=26, H1=64 (256 gates), H2=32 (128 gates), FC 32->16->10.
// 512 blocks x 128 threads, ONE batch elem per block, 2 blocks/CU target.
// __launch_bounds__(128,1): generous RA budget so packed weights STAY in VGPRs
// (r3/r4 with min-waves=2 made the RA rematerialize ~72 weight loads per step).
// Thread t: LSTM1 -> unit u=t>>1, rows {u,64+u} (t even: i,f) or {128+u,192+u}
// (t odd: g,o), full K=90 each, reads amortized over both rows.
// LSTM2 -> pair p=t>>1 (gates gtA=(p&1)*2, gtB=gtA+1 of unit v=p>>1), K-half hf=t&1.
// Gate exchange via shfl_down/shfl_xor (uniform delta -> DPP, VALU pipe).

typedef __hip_bfloat16 bf16;
typedef _Float16 h2v __attribute__((ext_vector_type(2)));

#define T_STEPS 1000
#define IN_DIM  26

__device__ __forceinline__ float bits2f(unsigned short h) {
    unsigned int u = ((unsigned int)h) << 16;
    return __uint_as_float(u);
}

__device__ __forceinline__ float ldv(const void* p, int idx, bool isb) {
    return isb ? bits2f(((const unsigned short*)p)[idx])
               : ((const float*)p)[idx];
}

__device__ __forceinline__ float sigm(float x) {
    return 1.0f / (1.0f + __expf(-x));
}

__device__ __forceinline__ float tanh_(float x) {
    float a = fabsf(x);
    float e = __expf(2.0f * a);
    float r = 1.0f - 2.0f / (e + 1.0f);
    return copysignf(r, x);
}

__device__ __forceinline__ float DOT2(h2v a, h2v b, float c) {
    return __builtin_amdgcn_fdot2(a, b, c, false);
}

__device__ __forceinline__ h2v pkh(float a, float b) {
    h2v r; r[0] = (_Float16)a; r[1] = (_Float16)b; return r;
}

__device__ __forceinline__ h2v f2h2(float f) {
    return __builtin_bit_cast(h2v, f);
}

__global__ __launch_bounds__(128, 1)
void lstm_fused(const void* __restrict__ x,
                const void* __restrict__ w_ih1, const void* __restrict__ w_hh1,
                const void* __restrict__ b_ih1, const void* __restrict__ b_hh1,
                const void* __restrict__ w_ih2, const void* __restrict__ w_hh2,
                const void* __restrict__ b_ih2, const void* __restrict__ b_hh2,
                const void* __restrict__ w_fc1, const void* __restrict__ b_fc1,
                const void* __restrict__ w_fc2, const void* __restrict__ b_fc2,
                void* __restrict__ out)
{
    const int t_ = threadIdx.x;        // 0..127
    const int b  = blockIdx.x;         // batch elem

    // LSTM1 mapping
    const int u1    = t_ >> 1;
    const int h1f   = t_ & 1;                          // 0: rows i,f  1: rows g,o
    const int rowA1 = h1f ? (128 + u1) : u1;
    const int rowB1 = h1f ? (192 + u1) : (64 + u1);

    // LSTM2 mapping (gate pairs x split-K)
    const int p     = t_ >> 1;
    const int hf    = t_ & 1;                          // K-half
    const int v2    = p >> 1;                          // unit 0..31
    const int gA2   = (p & 1) * 2;                     // 0 (i,f) or 2 (g,o)
    const int rowA2 = gA2 * 32 + v2;
    const int rowB2 = (gA2 + 1) * 32 + v2;

    __shared__ __align__(16) h2v xsh[2][16];    // 26 f16 + zero pad
    __shared__ __align__(16) h2v h1sh[2][32];   // 64 f16
    __shared__ __align__(16) h2v h2sh[2][16];   // 32 f16
    __shared__ __align__(16) float h2f[32];
    __shared__ __align__(16) float f1s[16];

    // ---- runtime dtype detection (block-uniform): w_ih1 ~ U(-1/8,1/8) ----
    bool isb = true;
    {
        const unsigned short* wu = (const unsigned short*)w_ih1;
        for (int k = 0; k < 64; ++k) {
            float v = fabsf(bits2f(wu[k]));
            if (!(v <= 0.1251f)) isb = false;
        }
    }

    // ---- weights into registers as packed half2 (144 h2 regs) ----
    h2v w1xa[16], w1xb[16], w1ha[32], w1hb[32];
    h2v w2xa[16], w2xb[16], w2ha[8], w2hb[8];
#define LOADW(ISB)                                                              \
    {                                                                           \
        _Pragma("unroll") for (int q = 0; q < 16; ++q) {                        \
            w1xa[q] = (q < 13) ? pkh(ldv(w_ih1, rowA1 * 26 + 2 * q, ISB),       \
                                     ldv(w_ih1, rowA1 * 26 + 2 * q + 1, ISB))   \
                               : pkh(0.f, 0.f);                                 \
            w1xb[q] = (q < 13) ? pkh(ldv(w_ih1, rowB1 * 26 + 2 * q, ISB),       \
                                     ldv(w_ih1, rowB1 * 26 + 2 * q + 1, ISB))   \
                               : pkh(0.f, 0.f);                                 \
        }                                                                       \
        _Pragma("unroll") for (int q = 0; q < 32; ++q) {                        \
            w1ha[q] = pkh(ldv(w_hh1, rowA1 * 64 + 2 * q, ISB),                  \
                          ldv(w_hh1, rowA1 * 64 + 2 * q + 1, ISB));             \
            w1hb[q] = pkh(ldv(w_hh1, rowB1 * 64 + 2 * q, ISB),                  \
                          ldv(w_hh1, rowB1 * 64 + 2 * q + 1, ISB));             \
        }                                                                       \
        _Pragma("unroll") for (int q = 0; q < 16; ++q) {                        \
            w2xa[q] = pkh(ldv(w_ih2, rowA2 * 64 + 32 * hf + 2 * q, ISB),        \
                          ldv(w_ih2, rowA2 * 64 + 32 * hf + 2 * q + 1, ISB));   \
            w2xb[q] = pkh(ldv(w_ih2, rowB2 * 64 + 32 * hf + 2 * q, ISB),        \
                          ldv(w_ih2, rowB2 * 64 + 32 * hf + 2 * q + 1, ISB));   \
        }                                                                       \
        _Pragma("unroll") for (int q = 0; q < 8; ++q) {                         \
            w2ha[q] = pkh(ldv(w_hh2, rowA2 * 32 + 16 * hf + 2 * q, ISB),        \
                          ldv(w_hh2, rowA2 * 32 + 16 * hf + 2 * q + 1, ISB));   \
            w2hb[q] = pkh(ldv(w_hh2, rowB2 * 32 + 16 * hf + 2 * q, ISB),        \
                          ldv(w_hh2, rowB2 * 32 + 16 * hf + 2 * q + 1, ISB));   \
        }                                                                       \
    }
    if (isb) LOADW(true) else LOADW(false)
#undef LOADW

    const float biasA1 = ldv(b_ih1, rowA1, isb) + ldv(b_hh1, rowA1, isb);
    const float biasB1 = ldv(b_ih1, rowB1, isb) + ldv(b_hh1, rowB1, isb);
    const float biasA2 = ldv(b_ih2, rowA2, isb) + ldv(b_hh2, rowA2, isb);
    const float biasB2 = ldv(b_ih2, rowB2, isb) + ldv(b_hh2, rowB2, isb);

    // ---- init state ----
    float c1 = 0.0f, c2 = 0.0f;
    if (t_ < 32) h1sh[1][t_] = pkh(0.f, 0.f);
    if (t_ < 16) h2sh[1][t_] = pkh(0.f, 0.f);
    {
        float x0 = (t_ < IN_DIM) ? ldv(x, b * (IN_DIM * T_STEPS) + t_ * T_STEPS, isb) : 0.f;
        float x0n = __shfl_down(x0, 1, 64);
        if (t_ < 32 && (t_ & 1) == 0) {
            xsh[0][t_ >> 1] = pkh(x0, x0n);
            xsh[1][t_ >> 1] = pkh(0.f, 0.f);
        }
    }
    __syncthreads();

    for (int t = 0; t < T_STEPS; ++t) {
        const int cur = t & 1, prv = cur ^ 1;

        // prefetch x[t+1] (consumed at staging before BAR-C)
        float px = 0.0f;
        const bool doPf = (t_ < IN_DIM) && (t + 1 < T_STEPS);
        if (doPf)
            px = ldv(x, b * (IN_DIM * T_STEPS) + t_ * T_STEPS + (t + 1), isb);

        // ---- Phase A: LSTM1 two gate rows per thread, K=26+64 ----
        float aA0 = 0.f, aA1 = 0.f, aA2 = 0.f, aA3 = 0.f;
        float aB0 = 0.f, aB1 = 0.f, aB2 = 0.f, aB3 = 0.f;
        {
            const float4* xv4 = (const float4*)xsh[cur];
#pragma unroll
            for (int q = 0; q < 4; ++q) {
                float4 v = xv4[q];
                aA0 = DOT2(w1xa[4*q+0], f2h2(v.x), aA0);
                aA1 = DOT2(w1xa[4*q+1], f2h2(v.y), aA1);
                aA2 = DOT2(w1xa[4*q+2], f2h2(v.z), aA2);
                aA3 = DOT2(w1xa[4*q+3], f2h2(v.w), aA3);
                aB0 = DOT2(w1xb[4*q+0], f2h2(v.x), aB0);
                aB1 = DOT2(w1xb[4*q+1], f2h2(v.y), aB1);
                aB2 = DOT2(w1xb[4*q+2], f2h2(v.z), aB2);
                aB3 = DOT2(w1xb[4*q+3], f2h2(v.w), aB3);
            }
            const float4* hv4 = (const float4*)h1sh[prv];
#pragma unroll
            for (int q = 0; q < 8; ++q) {
                float4 v = hv4[q];
                aA0 = DOT2(w1ha[4*q+0], f2h2(v.x), aA0);
                aA1 = DOT2(w1ha[4*q+1], f2h2(v.y), aA1);
                aA2 = DOT2(w1ha[4*q+2], f2h2(v.z), aA2);
                aA3 = DOT2(w1ha[4*q+3], f2h2(v.w), aA3);
                aB0 = DOT2(w1hb[4*q+0], f2h2(v.x), aB0);
                aB1 = DOT2(w1hb[4*q+1], f2h2(v.y), aB1);
                aB2 = DOT2(w1hb[4*q+2], f2h2(v.z), aB2);
                aB3 = DOT2(w1hb[4*q+3], f2h2(v.w), aB3);
            }
        }
        float paA = ((aA0 + aA1) + (aA2 + aA3)) + biasA1;
        float paB = ((aB0 + aB1) + (aB2 + aB3)) + biasB1;
        // even thread: (i,f) both sigmoid; odd thread: (g,o) = tanh, sigmoid
        float actA = h1f ? tanh_(paA) : sigm(paA);
        float actB = sigm(paB);

        // odd thread packs (g,o); even thread combines and updates c1/h1
        float gof = __shfl_down(__builtin_bit_cast(float, pkh(actA, actB)), 1, 64);
        float hval = 0.f;
        if (h1f == 0) {
            h2v g_o = __builtin_bit_cast(h2v, gof);
            c1 = fmaf(actB, c1, actA * (float)g_o[0]);   // f*c + i*g
            hval = (float)g_o[1] * tanh_(c1);            // o * tanh(c)
        }
        float hnb = __shfl_down(hval, 2, 64);
        if ((t_ & 3) == 0) h1sh[cur][t_ >> 2] = pkh(hval, hnb);
        __syncthreads();   // BAR-A: h1sh[cur] ready

        // ---- Phase C: LSTM2, two gates x half-K per thread (K-half=48) ----
        float bA0 = 0.f, bA1 = 0.f, bB0 = 0.f, bB1 = 0.f;
        {
            const float4* h1v = (const float4*)((const h2v*)h1sh[cur] + 16 * hf);
#pragma unroll
            for (int q = 0; q < 4; ++q) {
                float4 v = h1v[q];
                bA0 = DOT2(w2xa[4*q+0], f2h2(v.x), bA0);
                bA1 = DOT2(w2xa[4*q+1], f2h2(v.y), bA1);
                bA0 = DOT2(w2xa[4*q+2], f2h2(v.z), bA0);
                bA1 = DOT2(w2xa[4*q+3], f2h2(v.w), bA1);
                bB0 = DOT2(w2xb[4*q+0], f2h2(v.x), bB0);
                bB1 = DOT2(w2xb[4*q+1], f2h2(v.y), bB1);
                bB0 = DOT2(w2xb[4*q+2], f2h2(v.z), bB0);
                bB1 = DOT2(w2xb[4*q+3], f2h2(v.w), bB1);
            }
            const float4* h2vv = (const float4*)((const h2v*)h2sh[prv] + 8 * hf);
#pragma unroll
            for (int q = 0; q < 2; ++q) {
                float4 v = h2vv[q];
                bA0 = DOT2(w2ha[4*q+0], f2h2(v.x), bA0);
                bA1 = DOT2(w2ha[4*q+1], f2h2(v.y), bA1);
                bA0 = DOT2(w2ha[4*q+2], f2h2(v.z), bA0);
                bA1 = DOT2(w2ha[4*q+3], f2h2(v.w), bA1);
                bB0 = DOT2(w2hb[4*q+0], f2h2(v.x), bB0);
                bB1 = DOT2(w2hb[4*q+1], f2h2(v.y), bB1);
                bB0 = DOT2(w2hb[4*q+2], f2h2(v.z), bB0);
                bB1 = DOT2(w2hb[4*q+3], f2h2(v.w), bB1);
            }
        }
        float pbA = bA0 + bA1;  pbA += __shfl_xor(pbA, 1, 64);  pbA += biasA2;
        float pbB = bB0 + bB1;  pbB += __shfl_xor(pbB, 1, 64);  pbB += biasB2;
        // p even: (i,f) both sigmoid; p odd: (g,o) = tanh, sigmoid
        float actA2 = (p & 1) ? tanh_(pbA) : sigm(pbA);
        float actB2 = sigm(pbB);

        // thread t%4==0 (has i,f) combines with (g,o) from t+2
        float gof2 = __shfl_down(__builtin_bit_cast(float, pkh(actA2, actB2)), 2, 64);
        float hv2 = 0.f;
        if ((t_ & 3) == 0) {
            h2v g_o = __builtin_bit_cast(h2v, gof2);
            c2 = fmaf(actB2, c2, actA2 * (float)g_o[0]);
            hv2 = (float)g_o[1] * tanh_(c2);
        }
        float hnb2 = __shfl_down(hv2, 4, 64);
        if ((t_ & 7) == 0) h2sh[cur][t_ >> 3] = pkh(hv2, hnb2);

        // stage x[t+1] packed
        {
            float pxn = __shfl_down(px, 1, 64);
            if (doPf && ((t_ & 1) == 0))
                xsh[prv][t_ >> 1] = pkh(px, pxn);
        }
        __syncthreads();   // BAR-C
    }

    // ---- FC head: final h2 in h2sh[1] ((T-1)&1 == 1) ----
    if (t_ < 32) h2f[t_] = (float)(((const _Float16*)h2sh[1])[t_]);
    __syncthreads();
    if (t_ < 16) {
        float s = ldv(b_fc1, t_, isb);
#pragma unroll
        for (int k = 0; k < 32; ++k)
            s = fmaf(ldv(w_fc1, t_ * 32 + k, isb), h2f[k], s);
        f1s[t_] = fmaxf(s, 0.0f);
    }
    __syncthreads();
    if (t_ < 10) {
        float s = ldv(b_fc2, t_, isb);
#pragma unroll
        for (int k = 0; k < 16; ++k)
            s = fmaf(ldv(w_fc2, t_ * 16 + k, isb), f1s[k], s);
        int oidx = b * 10 + t_;
        if (isb) ((bf16*)out)[oidx] = __float2bfloat16(s);
        else     ((float*)out)[oidx] = s;
    }
}

extern "C" void kernel_launch(void* const* d_in, const int* in_sizes, int n_in,
                              void* d_out, int out_size, void* d_ws, size_t ws_size,
                              hipStream_t stream) {
    lstm_fused<<<dim3(512), dim3(128), 0, stream>>>(
        d_in[0], d_in[1], d_in[2], d_in[3], d_in[4],
        d_in[5], d_in[6], d_in[7], d_in[8],
        d_in[9], d_in[10], d_in[11], d_in[12], d_out);
}

// Round 6
// 1350.938 us; speedup vs baseline: 1.2403x; 1.2403x over previous
//
#include <hip/hip_runtime.h>
#include <hip/hip_bf16.h>

// AudioLSTM fused persistent kernel, v6.
// B=512, T=1000, IN=26, H1=64 (256 gates), H2=32 (128 gates), FC 32->16->10.
// 512 blocks x 256 threads, ONE elem per block -> 2 blocks/CU (2 waves/SIMD).
// amdgpu_waves_per_eu(2,2): pin occupancy so the scheduler/RA stops sinking
// the 72 packed weight registers back into the loop (r2-r5 all rematerialized).
// Weights packed half2 in VGPRs; x/h1/h2 packed half2 in LDS; v_dot2_f32_f16.
// LSTM1: thread j -> unit j>>2, gate j&3. LSTM2: unit j>>3, gate (j>>1)&3, K-half j&1.

typedef __hip_bfloat16 bf16;
typedef _Float16 h2v __attribute__((ext_vector_type(2)));

#define T_STEPS 1000
#define IN_DIM  26

__device__ __forceinline__ float bits2f(unsigned short h) {
    unsigned int u = ((unsigned int)h) << 16;
    return __uint_as_float(u);
}

// Branchless dtype-select load: both interpretations read in-bounds, select.
__device__ __forceinline__ float ldsel(const void* p, int idx, bool isb) {
    float a = bits2f(((const unsigned short*)p)[idx]);     // u16 idx: in-bounds either way
    float f = ((const float*)p)[isb ? (idx >> 1) : idx];   // stay in-bounds if data is 2B
    return isb ? a : f;
}

__device__ __forceinline__ float sigm(float x) {
    return 1.0f / (1.0f + __expf(-x));
}

__device__ __forceinline__ float tanh_(float x) {
    float a = fabsf(x);
    float e = __expf(2.0f * a);
    float r = 1.0f - 2.0f / (e + 1.0f);
    return copysignf(r, x);
}

__device__ __forceinline__ float DOT2(h2v a, h2v b, float c) {
    return __builtin_amdgcn_fdot2(a, b, c, false);
}

__device__ __forceinline__ h2v pkh(float a, float b) {
    h2v r; r[0] = (_Float16)a; r[1] = (_Float16)b; return r;
}

__device__ __forceinline__ h2v f2h2(float f) {
    return __builtin_bit_cast(h2v, f);
}

__global__
__attribute__((amdgpu_flat_work_group_size(256, 256), amdgpu_waves_per_eu(2, 2)))
void lstm_fused(const void* __restrict__ x,
                const void* __restrict__ w_ih1, const void* __restrict__ w_hh1,
                const void* __restrict__ b_ih1, const void* __restrict__ b_hh1,
                const void* __restrict__ w_ih2, const void* __restrict__ w_hh2,
                const void* __restrict__ b_ih2, const void* __restrict__ b_hh2,
                const void* __restrict__ w_fc1, const void* __restrict__ b_fc1,
                const void* __restrict__ w_fc2, const void* __restrict__ b_fc2,
                void* __restrict__ out)
{
    const int j    = threadIdx.x;       // 0..255
    const int lane = j & 63;
    const int b    = blockIdx.x;        // batch elem

    // LSTM1 mapping
    const int u1   = j >> 2;
    const int gt1  = j & 3;             // 0:i 1:f 2:g 3:o
    const int row1 = gt1 * 64 + u1;

    // LSTM2 mapping (split-K pairs)
    const int gt2  = (j >> 1) & 3;
    const int hf   = j & 1;
    const int row2 = gt2 * 32 + (j >> 3);

    __shared__ __align__(16) h2v xsh[2][16];     // 26 f16 + zero pad
    __shared__ __align__(16) h2v h1sh[2][32];    // 64 f16
    __shared__ __align__(16) h2v h2sh[2][16];    // 32 f16
    __shared__ __align__(16) float h2f[32];
    __shared__ __align__(16) float f1s[16];

    // ---- runtime dtype detection (block-uniform): w_ih1 ~ U(-1/8,1/8) ----
    bool isb = true;
    {
        const unsigned short* wu = (const unsigned short*)w_ih1;
        for (int k = 0; k < 64; ++k) {
            float v = fabsf(bits2f(wu[k]));
            if (!(v <= 0.1251f)) isb = false;
        }
    }

    // ---- weights into registers as packed half2 (72 regs), branchless ----
    h2v w1xp[16], w1hp[32], w2xp[16], w2hp[8];
#pragma unroll
    for (int q = 0; q < 16; ++q)
        w1xp[q] = (q < 13) ? pkh(ldsel(w_ih1, row1 * 26 + 2 * q, isb),
                                 ldsel(w_ih1, row1 * 26 + 2 * q + 1, isb))
                           : pkh(0.f, 0.f);
#pragma unroll
    for (int q = 0; q < 32; ++q)
        w1hp[q] = pkh(ldsel(w_hh1, row1 * 64 + 2 * q, isb),
                      ldsel(w_hh1, row1 * 64 + 2 * q + 1, isb));
#pragma unroll
    for (int q = 0; q < 16; ++q)
        w2xp[q] = pkh(ldsel(w_ih2, row2 * 64 + 32 * hf + 2 * q, isb),
                      ldsel(w_ih2, row2 * 64 + 32 * hf + 2 * q + 1, isb));
#pragma unroll
    for (int q = 0; q < 8; ++q)
        w2hp[q] = pkh(ldsel(w_hh2, row2 * 32 + 16 * hf + 2 * q, isb),
                      ldsel(w_hh2, row2 * 32 + 16 * hf + 2 * q + 1, isb));
    const float bias1 = ldsel(b_ih1, row1, isb) + ldsel(b_hh1, row1, isb);
    const float bias2 = ldsel(b_ih2, row2, isb) + ldsel(b_hh2, row2, isb);

    // ---- init state ----
    float c1 = 0.0f, c2 = 0.0f;
    if (j < 32) h1sh[1][j] = pkh(0.f, 0.f);
    if (j < 16) {
        h2sh[1][j] = pkh(0.f, 0.f);
        int k0 = 2 * j, k1 = 2 * j + 1;
        float v0 = (k0 < IN_DIM) ? ldsel(x, b * (IN_DIM * T_STEPS) + k0 * T_STEPS, isb) : 0.f;
        float v1 = (k1 < IN_DIM) ? ldsel(x, b * (IN_DIM * T_STEPS) + k1 * T_STEPS, isb) : 0.f;
        xsh[0][j] = pkh(v0, v1);
        xsh[1][j] = pkh(0.f, 0.f);
    }
    __syncthreads();

    for (int t = 0; t < T_STEPS; ++t) {
        const int cur = t & 1, prv = cur ^ 1;

        // prefetch x[t+1] (consumed at staging before BAR-C)
        float px = 0.0f;
        const bool doPf = (j < IN_DIM) && (t + 1 < T_STEPS);
        if (doPf)
            px = ldsel(x, b * (IN_DIM * T_STEPS) + j * T_STEPS + (t + 1), isb);

        // ---- Phase A: LSTM1 gate preact, K=64(h)+26(x) via dot2 ----
        // h-part first: h1sh[prv] has been stable since last iteration's BAR-A,
        // so these LDS reads issue without waiting on the most recent barrier.
        float a0 = 0.f, a1 = 0.f, a2 = 0.f, a3 = 0.f;
        {
            const float4* hv4 = (const float4*)h1sh[prv];
#pragma unroll
            for (int q = 0; q < 8; ++q) {
                float4 v = hv4[q];
                a0 = DOT2(w1hp[4*q+0], f2h2(v.x), a0);
                a1 = DOT2(w1hp[4*q+1], f2h2(v.y), a1);
                a2 = DOT2(w1hp[4*q+2], f2h2(v.z), a2);
                a3 = DOT2(w1hp[4*q+3], f2h2(v.w), a3);
            }
            const float4* xv4 = (const float4*)xsh[cur];
#pragma unroll
            for (int q = 0; q < 4; ++q) {
                float4 v = xv4[q];
                a0 = DOT2(w1xp[4*q+0], f2h2(v.x), a0);
                a1 = DOT2(w1xp[4*q+1], f2h2(v.y), a1);
                a2 = DOT2(w1xp[4*q+2], f2h2(v.z), a2);
                a3 = DOT2(w1xp[4*q+3], f2h2(v.w), a3);
            }
        }
        float pa  = ((a0 + a1) + (a2 + a3)) + bias1;
        float act = (gt1 == 2) ? tanh_(pa) : sigm(pa);

        // gather i,f,g,o (adjacent lanes); c1/h1 on gt==0 lanes; pack pairs
        {
            int base = lane & ~3;
            float gi = __shfl(act, base + 0, 64);
            float gf = __shfl(act, base + 1, 64);
            float gg = __shfl(act, base + 2, 64);
            float go = __shfl(act, base + 3, 64);
            float hv = 0.f;
            if (gt1 == 0) {
                c1 = fmaf(gf, c1, gi * gg);
                hv = go * tanh_(c1);
            }
            float hnb = __shfl_down(hv, 4, 64);   // neighbor unit's h
            if ((j & 7) == 0)
                h1sh[cur][j >> 3] = pkh(hv, hnb);
        }
        __syncthreads();   // BAR-A: h1sh[cur] ready

        // ---- Phase C: LSTM2 gate preact (split-K pairs, K=48 each) ----
        float b0 = 0.f, b1 = 0.f, b2 = 0.f, b3 = 0.f;
        {
            const float4* h1v = (const float4*)((const h2v*)h1sh[cur] + 16 * hf);
#pragma unroll
            for (int q = 0; q < 4; ++q) {
                float4 v = h1v[q];
                b0 = DOT2(w2xp[4*q+0], f2h2(v.x), b0);
                b1 = DOT2(w2xp[4*q+1], f2h2(v.y), b1);
                b2 = DOT2(w2xp[4*q+2], f2h2(v.z), b2);
                b3 = DOT2(w2xp[4*q+3], f2h2(v.w), b3);
            }
            const float4* h2vv = (const float4*)((const h2v*)h2sh[prv] + 8 * hf);
#pragma unroll
            for (int q = 0; q < 2; ++q) {
                float4 v = h2vv[q];
                b0 = DOT2(w2hp[4*q+0], f2h2(v.x), b0);
                b1 = DOT2(w2hp[4*q+1], f2h2(v.y), b1);
                b2 = DOT2(w2hp[4*q+2], f2h2(v.z), b2);
                b3 = DOT2(w2hp[4*q+3], f2h2(v.w), b3);
            }
        }
        float pb = (b0 + b1) + (b2 + b3);
        pb += __shfl_xor(pb, 1, 64);      // combine K-halves
        pb += bias2;
        float act2 = (gt2 == 2) ? tanh_(pb) : sigm(pb);

        // gather unit's 4 gates (even lanes of 8-group); c2/h2; pack pairs
        {
            int base8 = lane & ~7;
            float qi = __shfl(act2, base8 + 0, 64);
            float qf = __shfl(act2, base8 + 2, 64);
            float qg = __shfl(act2, base8 + 4, 64);
            float qo = __shfl(act2, base8 + 6, 64);
            float hv2 = 0.f;
            if ((j & 7) == 0) {
                c2 = fmaf(qf, c2, qi * qg);
                hv2 = qo * tanh_(c2);
            }
            float hnb2 = __shfl_down(hv2, 8, 64);
            if ((j & 15) == 0)
                h2sh[cur][j >> 4] = pkh(hv2, hnb2);
        }

        // stage x[t+1] packed
        {
            float pxn = __shfl_down(px, 1, 64);
            if (doPf && ((j & 1) == 0))
                xsh[prv][j >> 1] = pkh(px, pxn);
        }
        __syncthreads();   // BAR-C
    }

    // ---- FC head: final h2 is in h2sh[1] ((T-1)&1 == 1) ----
    if (j < 32) h2f[j] = (float)(((const _Float16*)h2sh[1])[j]);
    __syncthreads();
    if (j < 16) {
        float s = ldsel(b_fc1, j, isb);
#pragma unroll
        for (int k = 0; k < 32; ++k)
            s = fmaf(ldsel(w_fc1, j * 32 + k, isb), h2f[k], s);
        f1s[j] = fmaxf(s, 0.0f);
    }
    __syncthreads();
    if (j < 10) {
        float s = ldsel(b_fc2, j, isb);
#pragma unroll
        for (int k = 0; k < 16; ++k)
            s = fmaf(ldsel(w_fc2, j * 16 + k, isb), f1s[k], s);
        int oidx = b * 10 + j;
        if (isb) ((bf16*)out)[oidx] = __float2bfloat16(s);
        else     ((float*)out)[oidx] = s;
    }
}

extern "C" void kernel_launch(void* const* d_in, const int* in_sizes, int n_in,
                              void* d_out, int out_size, void* d_ws, size_t ws_size,
                              hipStream_t stream) {
    lstm_fused<<<dim3(512), dim3(256), 0, stream>>>(
        d_in[0], d_in[1], d_in[2], d_in[3], d_in[4],
        d_in[5], d_in[6], d_in[7], d_in[8],
        d_in[9], d_in[10], d_in[11], d_in[12], d_out);
}

// Round 7
// 936.384 us; speedup vs baseline: 1.7894x; 1.4427x over previous
//
#include <hip/hip_runtime.h>
#include <hip/hip_bf16.h>

// AudioLSTM fused persistent kernel, v7: wave-specialized pipeline.
// B=512, T=1000, IN=26, H1=64 (256 gates), H2=32 (128 gates), FC 32->16->10.
// 512 blocks x 256 threads, ONE elem per block -> 2 blocks/CU (2 waves/SIMD).
// Waves 0-1: LSTM1 (2 gate rows/thread, reads amortized).
// Wave 2:    LSTM2, pipelined ONE STEP BEHIND LSTM1 (h2[t] needs h1[t] only;
//            nothing in LSTM1 needs h2 -> removes LSTM2 from the critical path).
// Wave 3:    x[t+1] prefetch into double-buffered LDS.
// ONE barrier per step (was 2). All gate exchanges are quad-local shfl_xor
// (mask 1/2 -> DPP quad_perm, VALU pipe) -> zero ds_bpermute on the LDS pipe.

typedef __hip_bfloat16 bf16;
typedef _Float16 h2v __attribute__((ext_vector_type(2)));

#define T_STEPS 1000
#define IN_DIM  26

__device__ __forceinline__ float bits2f(unsigned short h) {
    unsigned int u = ((unsigned int)h) << 16;
    return __uint_as_float(u);
}

__device__ __forceinline__ float ldv(const void* p, int idx, bool isb) {
    return isb ? bits2f(((const unsigned short*)p)[idx])
               : ((const float*)p)[idx];
}

__device__ __forceinline__ float sigm(float x) {
    return 1.0f / (1.0f + __expf(-x));
}

__device__ __forceinline__ float tanh_(float x) {
    float a = fabsf(x);
    float e = __expf(2.0f * a);
    float r = 1.0f - 2.0f / (e + 1.0f);
    return copysignf(r, x);
}

__device__ __forceinline__ float DOT2(h2v a, h2v b, float c) {
    return __builtin_amdgcn_fdot2(a, b, c, false);
}

__device__ __forceinline__ h2v pkh(float a, float b) {
    h2v r; r[0] = (_Float16)a; r[1] = (_Float16)b; return r;
}

__device__ __forceinline__ h2v f2h2(float f) {
    return __builtin_bit_cast(h2v, f);
}

__global__
__attribute__((amdgpu_flat_work_group_size(256, 256), amdgpu_waves_per_eu(2, 2)))
void lstm_fused(const void* __restrict__ x,
                const void* __restrict__ w_ih1, const void* __restrict__ w_hh1,
                const void* __restrict__ b_ih1, const void* __restrict__ b_hh1,
                const void* __restrict__ w_ih2, const void* __restrict__ w_hh2,
                const void* __restrict__ b_ih2, const void* __restrict__ b_hh2,
                const void* __restrict__ w_fc1, const void* __restrict__ b_fc1,
                const void* __restrict__ w_fc2, const void* __restrict__ b_fc2,
                void* __restrict__ out)
{
    const int j    = threadIdx.x;       // 0..255
    const int wid  = j >> 6;            // wave id 0..3
    const int lane = j & 63;
    const int b    = blockIdx.x;        // batch elem

    __shared__ __align__(16) h2v xsh[2][16];     // 26 f16 + zero pad (pads stay 0)
    __shared__ __align__(16) h2v h1sh[2][32];    // 64 f16, dbuffered by step parity
    __shared__ __align__(16) h2v h2sh[2][16];    // 32 f16, dbuffered (wave-2 local)
    __shared__ __align__(16) float f1s[16];

    // ---- runtime dtype detection (uniform): w_ih1 ~ U(-1/8,1/8) ----
    bool isb = true;
    {
        const unsigned short* wu = (const unsigned short*)w_ih1;
        for (int k = 0; k < 64; ++k) {
            float v = fabsf(bits2f(wu[k]));
            if (!(v <= 0.1251f)) isb = false;
        }
    }

    // ---- init LDS state ----
    if (j < 32) h1sh[1][j] = pkh(0.f, 0.f);
    if (j < 16) h2sh[1][j] = pkh(0.f, 0.f);
    if (j >= 13 && j < 16) { xsh[0][j] = pkh(0.f, 0.f); xsh[1][j] = pkh(0.f, 0.f); }
    if (j < 13) {
        float v0 = ldv(x, b * (IN_DIM * T_STEPS) + (2 * j) * T_STEPS, isb);
        float v1 = (2 * j + 1 < IN_DIM)
                   ? ldv(x, b * (IN_DIM * T_STEPS) + (2 * j + 1) * T_STEPS, isb) : 0.f;
        xsh[0][j] = pkh(v0, v1);
    }
    __syncthreads();

    if (wid <= 1) {
        // ================= LSTM1: threads 0..127, 2 gate rows each =========
        const int t    = j;            // 0..127
        const int u    = t >> 1;       // unit 0..63
        const int sub  = t & 1;        // 0: rows (i,f)  1: rows (g,o)
        const int rowA = sub ? (128 + u) : u;         // g : i
        const int rowB = sub ? (192 + u) : (64 + u);  // o : f

        h2v wxA[16], wxB[16], whA[32], whB[32];
#pragma unroll
        for (int q = 0; q < 16; ++q) {
            wxA[q] = (q < 13) ? pkh(ldv(w_ih1, rowA * 26 + 2 * q, isb),
                                    ldv(w_ih1, rowA * 26 + 2 * q + 1, isb)) : pkh(0.f, 0.f);
            wxB[q] = (q < 13) ? pkh(ldv(w_ih1, rowB * 26 + 2 * q, isb),
                                    ldv(w_ih1, rowB * 26 + 2 * q + 1, isb)) : pkh(0.f, 0.f);
        }
#pragma unroll
        for (int q = 0; q < 32; ++q) {
            whA[q] = pkh(ldv(w_hh1, rowA * 64 + 2 * q, isb),
                         ldv(w_hh1, rowA * 64 + 2 * q + 1, isb));
            whB[q] = pkh(ldv(w_hh1, rowB * 64 + 2 * q, isb),
                         ldv(w_hh1, rowB * 64 + 2 * q + 1, isb));
        }
        const float biasA = ldv(b_ih1, rowA, isb) + ldv(b_hh1, rowA, isb);
        const float biasB = ldv(b_ih1, rowB, isb) + ldv(b_hh1, rowB, isb);

        float c1 = 0.0f;
        for (int s = 0; s <= T_STEPS; ++s) {
            if (s < T_STEPS) {
                const int cur = s & 1, prv = cur ^ 1;
                float aA0 = 0.f, aA1 = 0.f, aA2 = 0.f, aA3 = 0.f;
                float aB0 = 0.f, aB1 = 0.f, aB2 = 0.f, aB3 = 0.f;
                const float4* hv4 = (const float4*)h1sh[prv];
#pragma unroll
                for (int q = 0; q < 8; ++q) {
                    float4 v = hv4[q];
                    aA0 = DOT2(whA[4*q+0], f2h2(v.x), aA0);
                    aA1 = DOT2(whA[4*q+1], f2h2(v.y), aA1);
                    aA2 = DOT2(whA[4*q+2], f2h2(v.z), aA2);
                    aA3 = DOT2(whA[4*q+3], f2h2(v.w), aA3);
                    aB0 = DOT2(whB[4*q+0], f2h2(v.x), aB0);
                    aB1 = DOT2(whB[4*q+1], f2h2(v.y), aB1);
                    aB2 = DOT2(whB[4*q+2], f2h2(v.z), aB2);
                    aB3 = DOT2(whB[4*q+3], f2h2(v.w), aB3);
                }
                const float4* xv4 = (const float4*)xsh[cur];
#pragma unroll
                for (int q = 0; q < 4; ++q) {
                    float4 v = xv4[q];
                    aA0 = DOT2(wxA[4*q+0], f2h2(v.x), aA0);
                    aA1 = DOT2(wxA[4*q+1], f2h2(v.y), aA1);
                    aA2 = DOT2(wxA[4*q+2], f2h2(v.z), aA2);
                    aA3 = DOT2(wxA[4*q+3], f2h2(v.w), aA3);
                    aB0 = DOT2(wxB[4*q+0], f2h2(v.x), aB0);
                    aB1 = DOT2(wxB[4*q+1], f2h2(v.y), aB1);
                    aB2 = DOT2(wxB[4*q+2], f2h2(v.z), aB2);
                    aB3 = DOT2(wxB[4*q+3], f2h2(v.w), aB3);
                }
                float pA = ((aA0 + aA1) + (aA2 + aA3)) + biasA;
                float pB = ((aB0 + aB1) + (aB2 + aB3)) + biasB;
                float actA = sub ? tanh_(pA) : sigm(pA);   // g : i
                float actB = sigm(pB);                     // o : f
                // pair exchange (quad-local -> DPP quad_perm)
                float packed = __builtin_bit_cast(float, pkh(actA, actB));
                float other  = __shfl_xor(packed, 1, 64);
                float hval = 0.f;
                if (sub == 0) {
                    h2v g_o = __builtin_bit_cast(h2v, other);
                    c1 = fmaf(actB, c1, actA * (float)g_o[0]);  // f*c + i*g
                    hval = (float)g_o[1] * tanh_(c1);           // o*tanh(c)
                }
                float hnb = __shfl_xor(hval, 2, 64);            // quad-local
                if ((t & 3) == 0)
                    h1sh[cur][t >> 2] = pkh(hval, hnb);
            }
            __syncthreads();
        }
    } else if (wid == 2) {
        // ================= LSTM2: wave 2, one step behind ===================
        const int u    = lane >> 1;    // unit 0..31
        const int sub  = lane & 1;     // 0: rows (i,f)  1: rows (g,o)
        const int rowA = sub ? (64 + u) : u;          // g : i
        const int rowB = sub ? (96 + u) : (32 + u);   // o : f

        h2v wxA[32], wxB[32], whA[16], whB[16];
#pragma unroll
        for (int q = 0; q < 32; ++q) {
            wxA[q] = pkh(ldv(w_ih2, rowA * 64 + 2 * q, isb),
                         ldv(w_ih2, rowA * 64 + 2 * q + 1, isb));
            wxB[q] = pkh(ldv(w_ih2, rowB * 64 + 2 * q, isb),
                         ldv(w_ih2, rowB * 64 + 2 * q + 1, isb));
        }
#pragma unroll
        for (int q = 0; q < 16; ++q) {
            whA[q] = pkh(ldv(w_hh2, rowA * 32 + 2 * q, isb),
                         ldv(w_hh2, rowA * 32 + 2 * q + 1, isb));
            whB[q] = pkh(ldv(w_hh2, rowB * 32 + 2 * q, isb),
                         ldv(w_hh2, rowB * 32 + 2 * q + 1, isb));
        }
        const float biasA = ldv(b_ih2, rowA, isb) + ldv(b_hh2, rowA, isb);
        const float biasB = ldv(b_ih2, rowB, isb) + ldv(b_hh2, rowB, isb);

        float c2 = 0.0f;
        for (int s = 0; s <= T_STEPS; ++s) {
            if (s >= 1) {
                const int wb = (s - 1) & 1;   // tau = s-1
                float aA0 = 0.f, aA1 = 0.f, aA2 = 0.f, aA3 = 0.f;
                float aB0 = 0.f, aB1 = 0.f, aB2 = 0.f, aB3 = 0.f;
                const float4* hv4 = (const float4*)h1sh[wb];      // h1[tau]
#pragma unroll
                for (int q = 0; q < 8; ++q) {
                    float4 v = hv4[q];
                    aA0 = DOT2(wxA[4*q+0], f2h2(v.x), aA0);
                    aA1 = DOT2(wxA[4*q+1], f2h2(v.y), aA1);
                    aA2 = DOT2(wxA[4*q+2], f2h2(v.z), aA2);
                    aA3 = DOT2(wxA[4*q+3], f2h2(v.w), aA3);
                    aB0 = DOT2(wxB[4*q+0], f2h2(v.x), aB0);
                    aB1 = DOT2(wxB[4*q+1], f2h2(v.y), aB1);
                    aB2 = DOT2(wxB[4*q+2], f2h2(v.z), aB2);
                    aB3 = DOT2(wxB[4*q+3], f2h2(v.w), aB3);
                }
                const float4* pv4 = (const float4*)h2sh[wb ^ 1];  // h2[tau-1]
#pragma unroll
                for (int q = 0; q < 4; ++q) {
                    float4 v = pv4[q];
                    aA0 = DOT2(whA[4*q+0], f2h2(v.x), aA0);
                    aA1 = DOT2(whA[4*q+1], f2h2(v.y), aA1);
                    aA2 = DOT2(whA[4*q+2], f2h2(v.z), aA2);
                    aA3 = DOT2(whA[4*q+3], f2h2(v.w), aA3);
                    aB0 = DOT2(whB[4*q+0], f2h2(v.x), aB0);
                    aB1 = DOT2(whB[4*q+1], f2h2(v.y), aB1);
                    aB2 = DOT2(whB[4*q+2], f2h2(v.z), aB2);
                    aB3 = DOT2(whB[4*q+3], f2h2(v.w), aB3);
                }
                float pA = ((aA0 + aA1) + (aA2 + aA3)) + biasA;
                float pB = ((aB0 + aB1) + (aB2 + aB3)) + biasB;
                float actA = sub ? tanh_(pA) : sigm(pA);
                float actB = sigm(pB);
                float packed = __builtin_bit_cast(float, pkh(actA, actB));
                float other  = __shfl_xor(packed, 1, 64);
                float hval = 0.f;
                if (sub == 0) {
                    h2v g_o = __builtin_bit_cast(h2v, other);
                    c2 = fmaf(actB, c2, actA * (float)g_o[0]);
                    hval = (float)g_o[1] * tanh_(c2);
                }
                float hnb = __shfl_xor(hval, 2, 64);
                if ((lane & 3) == 0)
                    h2sh[wb][lane >> 2] = pkh(hval, hnb);   // h2[tau]
            }
            __syncthreads();
        }
    } else {
        // ================= wave 3: x prefetch ===============================
        for (int s = 0; s <= T_STEPS; ++s) {
            if (s + 1 < T_STEPS) {
                float px = 0.f;
                if (lane < IN_DIM)
                    px = ldv(x, b * (IN_DIM * T_STEPS) + lane * T_STEPS + (s + 1), isb);
                float pxn = __shfl_xor(px, 1, 64);
                if (lane < IN_DIM && ((lane & 1) == 0))
                    xsh[(s + 1) & 1][lane >> 1] = pkh(px, pxn);
            }
            __syncthreads();
        }
    }

    // ---- FC head: final h2[T-1] is in h2sh[1] ((T-1)&1 == 1) ----
    __syncthreads();
    if (j < 16) {
        float ss = ldv(b_fc1, j, isb);
        const _Float16* hp = (const _Float16*)h2sh[1];
#pragma unroll
        for (int k = 0; k < 32; ++k)
            ss = fmaf(ldv(w_fc1, j * 32 + k, isb), (float)hp[k], ss);
        f1s[j] = fmaxf(ss, 0.0f);
    }
    __syncthreads();
    if (j < 10) {
        float ss = ldv(b_fc2, j, isb);
#pragma unroll
        for (int k = 0; k < 16; ++k)
            ss = fmaf(ldv(w_fc2, j * 16 + k, isb), f1s[k], ss);
        int oidx = b * 10 + j;
        if (isb) ((bf16*)out)[oidx] = __float2bfloat16(ss);
        else     ((float*)out)[oidx] = ss;
    }
}

extern "C" void kernel_launch(void* const* d_in, const int* in_sizes, int n_in,
                              void* d_out, int out_size, void* d_ws, size_t ws_size,
                              hipStream_t stream) {
    lstm_fused<<<dim3(512), dim3(256), 0, stream>>>(
        d_in[0], d_in[1], d_in[2], d_in[3], d_in[4],
        d_in[5], d_in[6], d_in[7], d_in[8],
        d_in[9], d_in[10], d_in[11], d_in[12], d_out);
}